// Round 4
// baseline (293.565 us; speedup 1.0000x reference)
//
#include <hip/hip_runtime.h>

typedef float v4 __attribute__((ext_vector_type(4)));

#define D_MODEL 1024
#define D_STATE 64
#define CHUNK   256

// DPP-based cross-lane add: x + x[lane permuted by ctrl]. VALU pipe only.
__device__ __forceinline__ float dpp_add(float x, int ctrl) {
    int xi = __float_as_int(x);
    int yi;
    switch (ctrl) {  // ctrl must be a literal for the builtin; dispatch on constant
    case 0xB1:  yi = __builtin_amdgcn_update_dpp(xi, xi, 0xB1,  0xF, 0xF, false); break;
    case 0x4E:  yi = __builtin_amdgcn_update_dpp(xi, xi, 0x4E,  0xF, 0xF, false); break;
    default:    yi = __builtin_amdgcn_update_dpp(xi, xi, 0x128, 0xF, 0xF, false); break;
    }
    return x + __int_as_float(yi);
}

// Lane = 4 consecutive d (v4) x 8 n. Wave = 32 d x 64 n (y complete in-wave).
// n_grp on lane bits {0,1,3} -> reduction = quad_perm xor1, xor2, row_ror:8,
// all DPP (VALU pipe). No LDS, no barriers. B/C/u register-prefetched depth 2.
// grid = 64 bc x 32 d-segments = 2048 blocks of 64 -> 8 waves/CU = 2/SIMD.
__global__ __launch_bounds__(64, 2)
void YvParallelScan_kernel(const float* __restrict__ u,
                           const float* __restrict__ B,
                           const float* __restrict__ C,
                           const float* __restrict__ A_log,
                           float* __restrict__ out) {
    const int bc    = blockIdx.x >> 5;                       // 0..63
    const int dseg  = blockIdx.x & 31;                       // 0..31
    const int lane  = threadIdx.x;
    const int n_grp = (lane & 3) | ((lane & 8) >> 1);        // lane bits 0,1,3
    const int d_grp = ((lane & 4) >> 2) | ((lane & 48) >> 3);// lane bits 2,4,5
    const int d     = dseg * 32 + d_grp * 4;
    const int rowbase = bc * CHUNK;

    v4 a4[8], h4[8];
#pragma unroll
    for (int j = 0; j < 8; ++j) {
        const int n = n_grp * 8 + j;
        v4 al = *(const v4*)(A_log + (size_t)n * D_MODEL + d);
        v4 na;
        na[0] = -__expf(al[0]); na[1] = -__expf(al[1]);
        na[2] = -__expf(al[2]); na[3] = -__expf(al[3]);
        a4[j] = na;
        v4 z = {0.f, 0.f, 0.f, 0.f};
        h4[j] = z;
    }

    const v4* uptr = (const v4*)(u + (size_t)rowbase * D_MODEL + d);  // +256/t
    const v4* Bp   = (const v4*)(B + (size_t)rowbase * D_STATE + n_grp * 8); // +16/t
    const v4* Cp   = (const v4*)(C + (size_t)rowbase * D_STATE + n_grp * 8);
    v4*       optr = (v4*)(out + (size_t)rowbase * D_MODEL + d);

    // depth-2 register prefetch of x, B-slice, C-slice
    v4 xa = uptr[0],   xb = uptr[256];
    v4 Ba0 = Bp[0],  Ba1 = Bp[1],  Ca0 = Cp[0],  Ca1 = Cp[1];
    v4 Bb0 = Bp[16], Bb1 = Bp[17], Cb0 = Cp[16], Cb1 = Cp[17];

#pragma unroll 2
    for (int t = 0; t < CHUNK; ++t) {
        const int tp = (t + 2 < CHUNK) ? (t + 2) : (CHUNK - 1);
        v4 xn  = uptr[(size_t)tp * 256];
        v4 Bn0 = Bp[(size_t)tp * 16],     Bn1 = Bp[(size_t)tp * 16 + 1];
        v4 Cn0 = Cp[(size_t)tp * 16],     Cn1 = Cp[(size_t)tp * 16 + 1];

        const v4 x = xa;
        v4 acc0 = {0.f, 0.f, 0.f, 0.f};
        v4 acc1 = {0.f, 0.f, 0.f, 0.f};
#pragma unroll
        for (int j = 0; j < 4; ++j) {
            h4[j]     = a4[j]     * h4[j]     + Ba0[j] * x;
            acc0     += Ca0[j] * h4[j];
            h4[4 + j] = a4[4 + j] * h4[4 + j] + Ba1[j] * x;
            acc1     += Ca1[j] * h4[4 + j];
        }
        v4 acc = acc0 + acc1;

        // 8-way cross-lane sum over n_grp (lane bits 0,1,3): all-DPP butterfly
#pragma unroll
        for (int k = 0; k < 4; ++k) {
            float s = acc[k];
            s = dpp_add(s, 0xB1);    // quad_perm(1,0,3,2)  : xor 1
            s = dpp_add(s, 0x4E);    // quad_perm(2,3,0,1)  : xor 2
            s = dpp_add(s, 0x128);   // row_ror:8           : xor 8
            acc[k] = s;
        }

        if (n_grp == 0)
            optr[(size_t)t * 256] = acc;

        xa = xb; xb = xn;
        Ba0 = Bb0; Ba1 = Bb1; Ca0 = Cb0; Ca1 = Cb1;
        Bb0 = Bn0; Bb1 = Bn1; Cb0 = Cn0; Cb1 = Cn1;
    }
}

extern "C" void kernel_launch(void* const* d_in, const int* in_sizes, int n_in,
                              void* d_out, int out_size, void* d_ws, size_t ws_size,
                              hipStream_t stream) {
    const float* u     = (const float*)d_in[0];
    // d_in[1] = delta, unused by the reference forward
    const float* B     = (const float*)d_in[2];
    const float* C     = (const float*)d_in[3];
    const float* A_log = (const float*)d_in[4];
    float* out = (float*)d_out;

    YvParallelScan_kernel<<<2048, 64, 0, stream>>>(u, B, C, A_log, out);
}